// Round 4
// baseline (211.415 us; speedup 1.0000x reference)
//
#include <hip/hip_runtime.h>
#include <cstdint>
#include <cstddef>

// Problem constants
#define NB   32    // query batch
#define NSUP 25    // support images
#define KCLS 5     // classes
#define NC   512   // input channels
#define ND   128   // dk = dv
#define NP   196   // h*w
#define JS   208   // per-support padded spatial (13*16)
#define SHIFT 8.0f // fixed logit shift (softmax-invariant overflow guard)

typedef __attribute__((ext_vector_type(8))) short short8;   // 8 x bf16 (4 VGPRs)
typedef __attribute__((ext_vector_type(4))) float floatx4;  // MFMA C/D

__device__ inline short f2bf(float x) {
  union { float f; uint32_t u; } v; v.f = x;
  uint32_t r = (v.u + 0x7FFFu + ((v.u >> 16) & 1u)) >> 16;  // RNE
  return (short)(r & 0xFFFFu);
}
__device__ inline uint32_t pk2(float a, float b) {
  return (uint32_t)(uint16_t)f2bf(a) | ((uint32_t)(uint16_t)f2bf(b) << 16);
}

// ---------------------------------------------------------------------------
// Kernel 0: W fp32 -> bf16. Whi[mat][d:128][c:512], mats contiguous.
// ---------------------------------------------------------------------------
__global__ __launch_bounds__(256) void wconv_kernel(
    const float* __restrict__ Wqk, const float* __restrict__ Wv,
    uint16_t* __restrict__ Whi)
{
  const int f = (blockIdx.x * 256 + (int)threadIdx.x) * 8;   // < 131072
  const float* src = (f < ND * NC) ? (Wqk + f) : (Wv + f - ND * NC);
  short8 hv;
  #pragma unroll
  for (int i = 0; i < 8; ++i) hv[i] = f2bf(src[i]);
  *(short8*)(Whi + f) = hv;
}

// ---------------------------------------------------------------------------
// Kernel 1: fused projection GEMM (unchanged, verified).
//   QK: A=X(m=p), B=Wqk(n=d) -> bf16 Qt[b][p<196][d] / Kt[n][p:208][d]
//   V:  A=Wv(m=d), B=X(n=p)  -> bf16 Vt[n][d][p:208] / fp32 outVq[b][d][p]
// ---------------------------------------------------------------------------
__global__ __launch_bounds__(256) void gemm_kernel(
    const float* __restrict__ supp, const float* __restrict__ qry,
    const uint16_t* __restrict__ Whi,
    uint16_t* __restrict__ Qt, uint16_t* __restrict__ Kt,
    uint16_t* __restrict__ Vt, float* __restrict__ outVq)
{
  __shared__ uint16_t xs[16 * 520];     // 16.6 KB bf16 X tile, [p][c+pad]
  const int bx = blockIdx.x;
  const int t16 = bx % 13, img = bx / 13;
  const int tid = (int)threadIdx.x;
  const int w = tid >> 6, lane = tid & 63, ln = lane & 15, q = lane >> 4;
  const int d0 = w * 32;
  const int p0 = t16 * 16;

  const float* __restrict__ X = (img < NB)
      ? (qry  + (size_t)img * NC * NP)
      : (supp + (size_t)(img - NB) * NC * NP);

  // stage X tile as bf16: read float4 along p, write packed pairs along c
  #pragma unroll
  for (int k = 0; k < 4; ++k) {
    const int id = k * 256 + tid;
    const int cp = id >> 2;                        // c-pair: c = 2cp, 2cp+1
    const int pq = id & 3;
    int pg = p0 + pq * 4; if (pg > NP - 4) pg = NP - 4;   // clamp (pad rows masked later)
    const floatx4 fa = *(const floatx4*)(X + (2 * cp) * NP + pg);
    const floatx4 fb = *(const floatx4*)(X + (2 * cp + 1) * NP + pg);
    #pragma unroll
    for (int i = 0; i < 4; ++i)
      *((uint32_t*)xs + (pq * 4 + i) * 260 + cp) = pk2(fa[i], fb[i]);
  }
  __syncthreads();

  floatx4 aQ[2], aV[2];
  #pragma unroll
  for (int nt = 0; nt < 2; ++nt) {
    aQ[nt] = (floatx4){0.f, 0.f, 0.f, 0.f};
    aV[nt] = (floatx4){0.f, 0.f, 0.f, 0.f};
  }

  for (int ks = 0; ks < 16; ++ks) {
    const short8 xh = *(const short8*)&xs[ln * 520 + ks * 32 + q * 8];  // 1 ds_read_b128
    #pragma unroll
    for (int nt = 0; nt < 2; ++nt) {
      const size_t wr = (size_t)(d0 + nt * 16 + ln) * NC + ks * 32 + q * 8;
      const short8 wqh = *(const short8*)(Whi + wr);
      aQ[nt] = __builtin_amdgcn_mfma_f32_16x16x32_bf16(xh, wqh, aQ[nt], 0, 0, 0);
      const short8 wvh = *(const short8*)(Whi + (size_t)ND * NC + wr);
      aV[nt] = __builtin_amdgcn_mfma_f32_16x16x32_bf16(wvh, xh, aV[nt], 0, 0, 0);
    }
  }

  // QK: D row = p = p0+q*4+rr, col = d = d0+nt*16+ln
  if (img < NB) {
    #pragma unroll
    for (int nt = 0; nt < 2; ++nt)
      #pragma unroll
      for (int rr = 0; rr < 4; ++rr) {
        const int p = p0 + q * 4 + rr;
        if (p < NP)
          Qt[((size_t)img * NP + p) * ND + d0 + nt * 16 + ln] = (uint16_t)f2bf(aQ[nt][rr]);
      }
  } else {
    const int n = img - NB;
    #pragma unroll
    for (int nt = 0; nt < 2; ++nt)
      #pragma unroll
      for (int rr = 0; rr < 4; ++rr) {
        const int p = p0 + q * 4 + rr;              // 0..207, pads masked in attn
        Kt[((size_t)n * JS + p) * ND + d0 + nt * 16 + ln] = (uint16_t)f2bf(aQ[nt][rr]);
      }
  }
  // V: D row = d = d0+nt*16+q*4+rr, col = p = p0+ln
  const int p = p0 + ln;
  if (img < NB) {
    if (p < NP) {
      #pragma unroll
      for (int nt = 0; nt < 2; ++nt)
        #pragma unroll
        for (int rr = 0; rr < 4; ++rr)
          outVq[((size_t)img * ND + d0 + nt * 16 + q * 4 + rr) * NP + p] = aV[nt][rr];
    }
  } else {
    const int n = img - NB;
    #pragma unroll
    for (int nt = 0; nt < 2; ++nt)
      #pragma unroll
      for (int rr = 0; rr < 4; ++rr)
        Vt[((size_t)n * ND + d0 + nt * 16 + q * 4 + rr) * JS + p] = (uint16_t)f2bf(aV[nt][rr]);
  }
}

// ---------------------------------------------------------------------------
// Kernel 2: per-class masked attention — latency-bound redesign.
// NO LDS staging (Kt+Vt = 2.66 MB, L2-resident). 2-wave blocks (b-pair):
// both waves issue IDENTICAL K/V addresses (differ only in b) -> twin-wave
// L1 hits halve L2 traffic. grid = 16bq*5kc*13pt = 1040 -> 4 blocks/CU x
// 2 waves = 8 waves/CU with ZERO barriers.
// Register double-buffer pipeline with PINNED schedule:
//   LOAD(B,it+1); SB(0); COMP(A,it); SB(0); LOAD(A,it+2); SB(0); COMP(B,it+1)
// sched_barrier(0) forbids the compiler from sinking the 16 independent
// global_load_dwordx4 into the consuming chunk (the R1 failure): auto-
// waitcnt becomes a counted vmcnt(16) and loads fly under the previous
// chunk's ~500-cy compute. __launch_bounds__(128,2) grants 256 VGPRs for
// the ~200-VGPR live set. s_setprio(1) wraps MFMA clusters (T5).
// QK/exp/bpermute/PV math verbatim from the verified kernel.
// ---------------------------------------------------------------------------

// Load chunk CH's K/V fragments straight from global.
// K frag (A, m=j): lane(ln,q) -> Kt[(n*JS + j0 + ln)*ND + ks*32 + q*8]
// V frag (A, m=d): lane(ln,q) -> Vt[(n*ND + dt*16 + ln)*JS + jv[h] + (q&1)*8], h=q>>1
#define LOADF(BK, AV, CH) do {                                                 \
    _Pragma("unroll")                                                          \
    for (int t_ = 0; t_ < 2; ++t_) {                                           \
      const int tile16_ = (CH) * 2 + t_;                                       \
      int s_ = tile16_ / 13;                                                   \
      const int j0_ = (tile16_ - s_ * 13) * 16;                                \
      if (s_ > 4) s_ = 4;                                                      \
      const int n_ = (clsPack >> (6 * s_)) & 63;                               \
      const uint16_t* kr_ = Kt + ((size_t)(n_ * JS + j0_ + ln)) * ND + q * 8;  \
      _Pragma("unroll")                                                        \
      for (int ks_ = 0; ks_ < 4; ++ks_)                                        \
        BK[t_][ks_] = *(const short8*)(kr_ + ks_ * 32);                        \
    }                                                                          \
    {                                                                          \
      const int h_ = q >> 1;                                                   \
      const int ch_ = (CH) * 32 + h_ * 16;                                     \
      int sv_ = ch_ / JS, jv_ = ch_ - sv_ * JS;                                \
      if (sv_ > 4) { sv_ = 4; jv_ = 192; }                                     \
      const int n_ = (clsPack >> (6 * sv_)) & 63;                              \
      const uint16_t* vr_ = Vt + ((size_t)n_ * ND + ln) * JS + jv_ + (q & 1) * 8; \
      _Pragma("unroll")                                                        \
      for (int dt_ = 0; dt_ < 8; ++dt_)                                        \
        AV[dt_] = *(const short8*)(vr_ + (size_t)(dt_ * 16) * JS);             \
    }                                                                          \
  } while (0)

// QK as S^T (A=K m=j, B=Q n=p), exp with pad masking, packed bpermute
// D-layout -> B-operand transform, PV accumulate. Verbatim math.
#define COMPF(BK, AV, CH) do {                                                 \
    floatx4 e0_, e1_;                                                          \
    _Pragma("unroll")                                                          \
    for (int t_ = 0; t_ < 2; ++t_) {                                           \
      const int tile16_ = (CH) * 2 + t_;                                       \
      const int s_ = tile16_ / 13;                                             \
      const int j0_ = (tile16_ - s_ * 13) * 16;                                \
      const bool tval_ = (s_ < 5);                                             \
      floatx4 d4_ = {0.f, 0.f, 0.f, 0.f};                                      \
      __builtin_amdgcn_s_setprio(1);                                           \
      _Pragma("unroll")                                                        \
      for (int ks_ = 0; ks_ < 4; ++ks_)                                        \
        d4_ = __builtin_amdgcn_mfma_f32_16x16x32_bf16(BK[t_][ks_], aq[ks_], d4_, 0, 0, 0); \
      __builtin_amdgcn_s_setprio(0);                                           \
      floatx4 ev_;                                                             \
      _Pragma("unroll")                                                        \
      for (int r_ = 0; r_ < 4; ++r_) {                                         \
        const int j_ = j0_ + q * 4 + r_;                                       \
        const float e_ = (tval_ && j_ < NP) ? __expf(d4_[r_] - SHIFT) : 0.f;   \
        ev_[r_] = e_;                                                          \
        Ssum += e_;                                                            \
      }                                                                        \
      if (t_ == 0) e0_ = ev_; else e1_ = ev_;                                  \
    }                                                                          \
    short8 bp_;                                                                \
    _Pragma("unroll")                                                          \
    for (int r_ = 0; r_ < 4; ++r_) {                                           \
      const uint32_t pe_ = pk2(e0_[r_], e1_[r_]);                              \
      const int lo_ = __builtin_amdgcn_ds_bpermute(alo, (int)pe_);             \
      const int hi_ = __builtin_amdgcn_ds_bpermute(alo + 64, (int)pe_);        \
      bp_[r_]     = (short)(uint16_t)(hiTile ? (lo_ >> 16) : (lo_ & 0xFFFF));  \
      bp_[4 + r_] = (short)(uint16_t)(hiTile ? (hi_ >> 16) : (hi_ & 0xFFFF));  \
    }                                                                          \
    __builtin_amdgcn_s_setprio(1);                                             \
    _Pragma("unroll")                                                          \
    for (int dt_ = 0; dt_ < 8; ++dt_)                                          \
      acc[dt_] = __builtin_amdgcn_mfma_f32_16x16x32_bf16(AV[dt_], bp_, acc[dt_], 0, 0, 0); \
    __builtin_amdgcn_s_setprio(0);                                             \
  } while (0)

__global__ __launch_bounds__(128, 2) void attn_kernel(
    const uint16_t* __restrict__ Qt, const uint16_t* __restrict__ Kt,
    const uint16_t* __restrict__ Vt, const int* __restrict__ labels,
    float* __restrict__ out)
{
  const int bx = blockIdx.x;              // 1040 = 16bq*5kc*13pt
  const int pt = bx % 13;
  const int rem = bx / 13;                // 80 = 16*5
  const int kc = rem % KCLS;
  const int bq = rem / KCLS;              // 0..15
  const int p0 = pt * 16;
  const int tid = (int)threadIdx.x;
  const int w = tid >> 6, lane = tid & 63, ln = lane & 15, q = lane >> 4;
  const int b = bq * 2 + w;               // this wave's batch

  // class-support list packed in a register (6 bits/slot) via ballot
  const int myl = (lane < NSUP) ? labels[lane] : -1;
  unsigned long long m = __ballot(myl == kc);
  int clsPack = 0;
  #pragma unroll
  for (int s = 0; s < 5; ++s) {
    const int n = (m != 0ull) ? (int)__builtin_ctzll(m) : 0;
    clsPack |= n << (6 * s);
    m &= (m - 1);
  }
  clsPack = __builtin_amdgcn_readfirstlane(clsPack);   // force SALU decode

  // Q B-frags (resident): B[n=p][k=d]
  short8 aq[4];
  {
    int p = p0 + ln; if (p > NP - 1) p = NP - 1;
    const uint16_t* base = Qt + ((size_t)b * NP + p) * ND + q * 8;
    #pragma unroll
    for (int ks = 0; ks < 4; ++ks) aq[ks] = *(const short8*)(base + ks * 32);
  }

  floatx4 acc[8];
  #pragma unroll
  for (int dt = 0; dt < 8; ++dt) acc[dt] = (floatx4){0.f, 0.f, 0.f, 0.f};
  float Ssum = 0.f;

  const int alo = (ln + ((q & 1) << 5)) << 2;  // bpermute byte addr (verified)
  const bool hiTile = (q >= 2);

  // register double-buffered chunk pipeline: 33 chunks, pinned schedule
  short8 bkA[2][4], avA[8], bkB[2][4], avB[8];
  LOADF(bkA, avA, 0);
  __builtin_amdgcn_sched_barrier(0);
  #pragma unroll 1
  for (int it = 0; it < 32; it += 2) {
    LOADF(bkB, avB, it + 1);          // issue next chunk's 16 loads
    __builtin_amdgcn_sched_barrier(0);
    COMPF(bkA, avA, it);              // compute current while they fly
    __builtin_amdgcn_sched_barrier(0);
    LOADF(bkA, avA, it + 2);          // it+2 <= 32, always valid
    __builtin_amdgcn_sched_barrier(0);
    COMPF(bkB, avB, it + 1);
    __builtin_amdgcn_sched_barrier(0);
  }
  COMPF(bkA, avA, 32);                // tail chunk

  // ---- normalize and store (per wave; no merge needed) ----
  float sv = Ssum;
  sv += __shfl_xor(sv, 16);
  sv += __shfl_xor(sv, 32);
  const float inv = 1.f / sv;
  const int pp = p0 + ln;
  if (pp < NP) {
    float* ob = out + ((size_t)(b * KCLS + kc) * ND + q * 4) * NP + pp;
    #pragma unroll
    for (int dt = 0; dt < 8; ++dt)
      #pragma unroll
      for (int rr = 0; rr < 4; ++rr)
        ob[(size_t)(dt * 16 + rr) * NP] = acc[dt][rr] * inv;
  }
}

// ---------------------------------------------------------------------------
extern "C" void kernel_launch(void* const* d_in, const int* in_sizes, int n_in,
                              void* d_out, int out_size, void* d_ws, size_t ws_size,
                              hipStream_t stream) {
  const float* supp   = (const float*)d_in[0];
  const float* qry    = (const float*)d_in[1];
  const int*   labels = (const int*)d_in[2];
  const float* Wqk    = (const float*)d_in[3];
  const float* Wv     = (const float*)d_in[4];
  float* out = (float*)d_out;

  // ws layout (~4.6 MB)
  uint16_t* Whi = (uint16_t*)d_ws;                  // [2][128][512]
  uint16_t* Qt  = Whi + (size_t)2 * ND * NC;        // [32][196][128]
  uint16_t* Kt  = Qt  + (size_t)NB * NP * ND;       // [25][208][128]
  uint16_t* Vt  = Kt  + (size_t)NSUP * JS * ND;     // [25][128][208]
  float* outVq = out + (size_t)NB * KCLS * ND * NP; // query_v_flat region

  wconv_kernel<<<64, 256, 0, stream>>>(Wqk, Wv, Whi);
  gemm_kernel<<<741, 256, 0, stream>>>(supp, qry, Whi, Qt, Kt, Vt, outVq);
  attn_kernel<<<1040, 128, 0, stream>>>(Qt, Kt, Vt, labels, out);
}

// Round 5
// 165.864 us; speedup vs baseline: 1.2746x; 1.2746x over previous
//
#include <hip/hip_runtime.h>
#include <cstdint>
#include <cstddef>

// Problem constants
#define NB   32    // query batch
#define NSUP 25    // support images
#define KCLS 5     // classes
#define NC   512   // input channels
#define ND   128   // dk = dv
#define NP   196   // h*w
#define JS   208   // per-support padded spatial (13*16)
#define SHIFT 8.0f // fixed logit shift (softmax-invariant overflow guard)

// attn LDS staging geometry (R0-verbatim)
#define KPITCH 272             // 256B K row + 16B pad (bank-stride 68 dw -> 2-way)
#define KTILE  (16 * KPITCH)   // 4352 B per 16-j K tile
#define KBUF   (2 * KTILE)     // 8704 B
#define VPITCH 80              // 64B V row + 16B pad (bank-stride 20 dw -> 2-way)
#define VBUF   (128 * VPITCH)  // 10240 B
#define BUFSZ  (KBUF + VBUF)   // 18944 B per buffer

#define NGRP   (NB * KCLS * 13)          // 2080 (b,kc,pt) groups
#define PACC_F ((size_t)NGRP * 2 * 2048) // partial acc floats (2 halves)
#define PSUM_F ((size_t)NGRP * 2 * 16)   // partial Ssum floats

typedef __attribute__((ext_vector_type(8))) short short8;   // 8 x bf16 (4 VGPRs)
typedef __attribute__((ext_vector_type(4))) float floatx4;  // MFMA C/D

__device__ inline short f2bf(float x) {
  union { float f; uint32_t u; } v; v.f = x;
  uint32_t r = (v.u + 0x7FFFu + ((v.u >> 16) & 1u)) >> 16;  // RNE
  return (short)(r & 0xFFFFu);
}
__device__ inline uint32_t pk2(float a, float b) {
  return (uint32_t)(uint16_t)f2bf(a) | ((uint32_t)(uint16_t)f2bf(b) << 16);
}

// ---------------------------------------------------------------------------
// Kernel 0: W fp32 -> bf16. Whi[mat][d:128][c:512], mats contiguous.
// ---------------------------------------------------------------------------
__global__ __launch_bounds__(256) void wconv_kernel(
    const float* __restrict__ Wqk, const float* __restrict__ Wv,
    uint16_t* __restrict__ Whi)
{
  const int f = (blockIdx.x * 256 + (int)threadIdx.x) * 8;   // < 131072
  const float* src = (f < ND * NC) ? (Wqk + f) : (Wv + f - ND * NC);
  short8 hv;
  #pragma unroll
  for (int i = 0; i < 8; ++i) hv[i] = f2bf(src[i]);
  *(short8*)(Whi + f) = hv;
}

// ---------------------------------------------------------------------------
// Kernel 1: fused projection GEMM (unchanged, verified).
//   QK: A=X(m=p), B=Wqk(n=d) -> bf16 Qt[b][p<196][d] / Kt[n][p:208][d]
//   V:  A=Wv(m=d), B=X(n=p)  -> bf16 Vt[n][d][p:208] / fp32 outVq[b][d][p]
// ---------------------------------------------------------------------------
__global__ __launch_bounds__(256) void gemm_kernel(
    const float* __restrict__ supp, const float* __restrict__ qry,
    const uint16_t* __restrict__ Whi,
    uint16_t* __restrict__ Qt, uint16_t* __restrict__ Kt,
    uint16_t* __restrict__ Vt, float* __restrict__ outVq)
{
  __shared__ uint16_t xs[16 * 520];     // 16.6 KB bf16 X tile, [p][c+pad]
  const int bx = blockIdx.x;
  const int t16 = bx % 13, img = bx / 13;
  const int tid = (int)threadIdx.x;
  const int w = tid >> 6, lane = tid & 63, ln = lane & 15, q = lane >> 4;
  const int d0 = w * 32;
  const int p0 = t16 * 16;

  const float* __restrict__ X = (img < NB)
      ? (qry  + (size_t)img * NC * NP)
      : (supp + (size_t)(img - NB) * NC * NP);

  // stage X tile as bf16: read float4 along p, write packed pairs along c
  #pragma unroll
  for (int k = 0; k < 4; ++k) {
    const int id = k * 256 + tid;
    const int cp = id >> 2;                        // c-pair: c = 2cp, 2cp+1
    const int pq = id & 3;
    int pg = p0 + pq * 4; if (pg > NP - 4) pg = NP - 4;   // clamp (pad rows masked later)
    const floatx4 fa = *(const floatx4*)(X + (2 * cp) * NP + pg);
    const floatx4 fb = *(const floatx4*)(X + (2 * cp + 1) * NP + pg);
    #pragma unroll
    for (int i = 0; i < 4; ++i)
      *((uint32_t*)xs + (pq * 4 + i) * 260 + cp) = pk2(fa[i], fb[i]);
  }
  __syncthreads();

  floatx4 aQ[2], aV[2];
  #pragma unroll
  for (int nt = 0; nt < 2; ++nt) {
    aQ[nt] = (floatx4){0.f, 0.f, 0.f, 0.f};
    aV[nt] = (floatx4){0.f, 0.f, 0.f, 0.f};
  }

  for (int ks = 0; ks < 16; ++ks) {
    const short8 xh = *(const short8*)&xs[ln * 520 + ks * 32 + q * 8];  // 1 ds_read_b128
    #pragma unroll
    for (int nt = 0; nt < 2; ++nt) {
      const size_t wr = (size_t)(d0 + nt * 16 + ln) * NC + ks * 32 + q * 8;
      const short8 wqh = *(const short8*)(Whi + wr);
      aQ[nt] = __builtin_amdgcn_mfma_f32_16x16x32_bf16(xh, wqh, aQ[nt], 0, 0, 0);
      const short8 wvh = *(const short8*)(Whi + (size_t)ND * NC + wr);
      aV[nt] = __builtin_amdgcn_mfma_f32_16x16x32_bf16(wvh, xh, aV[nt], 0, 0, 0);
    }
  }

  // QK: D row = p = p0+q*4+rr, col = d = d0+nt*16+ln
  if (img < NB) {
    #pragma unroll
    for (int nt = 0; nt < 2; ++nt)
      #pragma unroll
      for (int rr = 0; rr < 4; ++rr) {
        const int p = p0 + q * 4 + rr;
        if (p < NP)
          Qt[((size_t)img * NP + p) * ND + d0 + nt * 16 + ln] = (uint16_t)f2bf(aQ[nt][rr]);
      }
  } else {
    const int n = img - NB;
    #pragma unroll
    for (int nt = 0; nt < 2; ++nt)
      #pragma unroll
      for (int rr = 0; rr < 4; ++rr) {
        const int p = p0 + q * 4 + rr;              // 0..207, pads masked in attn
        Kt[((size_t)n * JS + p) * ND + d0 + nt * 16 + ln] = (uint16_t)f2bf(aQ[nt][rr]);
      }
  }
  // V: D row = d = d0+nt*16+q*4+rr, col = p = p0+ln
  const int p = p0 + ln;
  if (img < NB) {
    if (p < NP) {
      #pragma unroll
      for (int nt = 0; nt < 2; ++nt)
        #pragma unroll
        for (int rr = 0; rr < 4; ++rr)
          outVq[((size_t)img * ND + d0 + nt * 16 + q * 4 + rr) * NP + p] = aV[nt][rr];
    }
  } else {
    const int n = img - NB;
    #pragma unroll
    for (int nt = 0; nt < 2; ++nt)
      #pragma unroll
      for (int rr = 0; rr < 4; ++rr)
        Vt[((size_t)n * ND + d0 + nt * 16 + q * 4 + rr) * JS + p] = (uint16_t)f2bf(aV[nt][rr]);
  }
}

// ---------------------------------------------------------------------------
// Kernel 2: per-class masked attention — R0-verbatim inner loop, j-SPLIT
// across 2 blocks for 2x occupancy (latency-bound fix).
// PART=true:  grid 1040 = 13pt * 5kc * (8bq * 2half); each block runs 17 of
//             34 padded chunks (chunk 33 fully masked, e=0 exact) and writes
//             UNNORMALIZED acc + partial Ssum to workspace. LDS 37.9KB x 4
//             blocks/CU = 151.5KB <= 160KB -> 16 waves/CU (2x R0).
// PART=false: grid 520, R0-verbatim single-pass (ws-too-small fallback).
// ---------------------------------------------------------------------------
template <int NCHUNK, bool PART>
__global__ __launch_bounds__(256, 2) void attn_kernel(
    const uint16_t* __restrict__ Qt, const uint16_t* __restrict__ Kt,
    const uint16_t* __restrict__ Vt, const int* __restrict__ labels,
    float* __restrict__ out, float* __restrict__ pacc, float* __restrict__ psum)
{
  __shared__ __align__(16) char smem[2 * BUFSZ];   // 37.9 KB double buffer

  const int bx = blockIdx.x;
  const int pt = bx % 13;
  const int rem = bx / 13;                // PART: 80 = 5*16 ; full: 40 = 5*8
  const int kc = rem % KCLS;
  const int rest = rem / KCLS;            // PART: 0..15 ; full: 0..7
  const int bq = PART ? (rest & 7) : rest;
  const int half = PART ? (rest >> 3) : 0;
  const int c0 = half * NCHUNK;           // chunk range [c0, c0+NCHUNK)
  const int b0 = bq * 4;                  // batch quad base
  const int p0 = pt * 16;
  const int tid = (int)threadIdx.x;
  const int w = tid >> 6, lane = tid & 63, ln = lane & 15, q = lane >> 4;
  const int b = b0 + w;                   // this wave's batch

  // class-support list packed in a register (6 bits/slot) via ballot
  const int myl = (lane < NSUP) ? labels[lane] : -1;
  unsigned long long m = __ballot(myl == kc);
  int clsPack = 0;
  #pragma unroll
  for (int s = 0; s < 5; ++s) {
    const int n = (m != 0ull) ? (int)__builtin_ctzll(m) : 0;
    clsPack |= n << (6 * s);
    m &= (m - 1);
  }

  // Q B-frags (resident): B[n=p][k=d]
  short8 aq[4];
  {
    int p = p0 + ln; if (p > NP - 1) p = NP - 1;
    const uint16_t* base = Qt + ((size_t)b * NP + p) * ND + q * 8;
    #pragma unroll
    for (int ks = 0; ks < 4; ++ks) aq[ks] = *(const short8*)(base + ks * 32);
  }

  floatx4 acc[8];
  #pragma unroll
  for (int dt = 0; dt < 8; ++dt) acc[dt] = (floatx4){0.f, 0.f, 0.f, 0.f};
  float Ssum = 0.f;

  const int alo = (ln + ((q & 1) << 5)) << 2;  // bpermute byte addr (verified)
  const bool hiTile = (q >= 2);

  // ---- chunk staging (R0-verbatim slots; chunk index offset by c0) ----
  // K: slots 0..511:  t=slot>>8, r=(slot>>4)&15, sc=slot&15
  // V: slots 512..1023: h, d, sc2 -> scol = h*2+sc2
  int4 pf[4];
  {
    // prefetch chunk c0
    int nk[2], j0k[2], nv[2], jv[2];
    #pragma unroll
    for (int t = 0; t < 2; ++t) {
      const int tile16 = c0 * 2 + t;
      int s = tile16 / 13;
      j0k[t] = (tile16 - s * 13) * 16;
      if (s > 4) s = 4;
      nk[t] = (clsPack >> (6 * s)) & 63;
    }
    #pragma unroll
    for (int h = 0; h < 2; ++h) {
      const int ch = c0 * 32 + h * 16;
      int sv = ch / JS, jvv = ch - sv * JS;
      if (sv > 4) { sv = 4; jvv = 192; }
      nv[h] = (clsPack >> (6 * sv)) & 63;
      jv[h] = jvv;
    }
    #pragma unroll
    for (int pass = 0; pass < 4; ++pass) {
      const int slot = pass * 256 + tid;
      if (pass < 2) {
        const int t = slot >> 8, r = (slot >> 4) & 15, sc = slot & 15;
        pf[pass] = *(const int4*)(Kt + ((size_t)(nk[t] * JS + j0k[t] + r)) * ND + sc * 8);
      } else {
        const int vs = slot - 512;
        const int h = vs >> 8, d = (vs >> 1) & 127, sc2 = vs & 1;
        pf[pass] = *(const int4*)(Vt + ((size_t)(nv[h] * ND + d)) * JS + jv[h] + sc2 * 8);
      }
    }
    char* db = smem;                    // buffer 0
    #pragma unroll
    for (int pass = 0; pass < 4; ++pass) {
      const int slot = pass * 256 + tid;
      if (pass < 2) {
        const int t = slot >> 8, r = (slot >> 4) & 15, sc = slot & 15;
        *(int4*)(db + t * KTILE + r * KPITCH + sc * 16) = pf[pass];
      } else {
        const int vs = slot - 512;
        const int h = vs >> 8, d = (vs >> 1) & 127, sc2 = vs & 1;
        *(int4*)(db + KBUF + d * VPITCH + (h * 2 + sc2) * 16) = pf[pass];
      }
    }
  }
  __syncthreads();

  for (int li = 0; li < NCHUNK; ++li) {
    const int cc = c0 + li;               // current chunk
    const int nc = cc + 1;                // next chunk
    int nk[2], j0k[2], nv[2], jv[2];
    if (li < NCHUNK - 1) {                // issue next chunk's global loads early
      #pragma unroll
      for (int t = 0; t < 2; ++t) {
        const int tile16 = nc * 2 + t;
        int s = tile16 / 13;
        j0k[t] = (tile16 - s * 13) * 16;
        if (s > 4) s = 4;
        nk[t] = (clsPack >> (6 * s)) & 63;
      }
      #pragma unroll
      for (int h = 0; h < 2; ++h) {
        const int ch = nc * 32 + h * 16;
        int sv = ch / JS, jvv = ch - sv * JS;
        if (sv > 4) { sv = 4; jvv = 192; }
        nv[h] = (clsPack >> (6 * sv)) & 63;
        jv[h] = jvv;
      }
      #pragma unroll
      for (int pass = 0; pass < 4; ++pass) {
        const int slot = pass * 256 + tid;
        if (pass < 2) {
          const int t = slot >> 8, r = (slot >> 4) & 15, sc = slot & 15;
          pf[pass] = *(const int4*)(Kt + ((size_t)(nk[t] * JS + j0k[t] + r)) * ND + sc * 8);
        } else {
          const int vs = slot - 512;
          const int h = vs >> 8, d = (vs >> 1) & 127, sc2 = vs & 1;
          pf[pass] = *(const int4*)(Vt + ((size_t)(nv[h] * ND + d)) * JS + jv[h] + sc2 * 8);
        }
      }
    }

    // ---- compute chunk `cc` from buffer li&1 ----
    const char* kb = smem + (li & 1) * BUFSZ;
    const char* vb = kb + KBUF;

    short8 av[8];
    #pragma unroll
    for (int dt = 0; dt < 8; ++dt)
      av[dt] = *(const short8*)(vb + (dt * 16 + ln) * VPITCH + q * 16);

    short8 bk[2][4];
    #pragma unroll
    for (int t = 0; t < 2; ++t)
      #pragma unroll
      for (int ks = 0; ks < 4; ++ks)
        bk[t][ks] = *(const short8*)(kb + t * KTILE + ln * KPITCH + ks * 64 + q * 16);

    // QK as S^T (A=K m=j, B=Q n=p), exp with pad masking (R0 verbatim)
    floatx4 e0, e1;
    #pragma unroll
    for (int t = 0; t < 2; ++t) {
      const int tile16 = cc * 2 + t;
      const int s = tile16 / 13;
      const int j0 = (tile16 - s * 13) * 16;
      const bool tval = (s < 5);
      floatx4 d4 = {0.f, 0.f, 0.f, 0.f};
      #pragma unroll
      for (int ks = 0; ks < 4; ++ks)
        d4 = __builtin_amdgcn_mfma_f32_16x16x32_bf16(bk[t][ks], aq[ks], d4, 0, 0, 0);
      floatx4 ev;
      #pragma unroll
      for (int r = 0; r < 4; ++r) {
        const int j = j0 + q * 4 + r;
        const float e = (tval && j < NP) ? __expf(d4[r] - SHIFT) : 0.f;
        ev[r] = e;
        Ssum += e;
      }
      if (t == 0) e0 = ev; else e1 = ev;
    }

    // D-layout -> B-operand transform (R0-verbatim packed exchange)
    short8 bp;
    #pragma unroll
    for (int r = 0; r < 4; ++r) {
      const uint32_t pe = pk2(e0[r], e1[r]);
      const int lo = __builtin_amdgcn_ds_bpermute(alo, (int)pe);
      const int hi = __builtin_amdgcn_ds_bpermute(alo + 64, (int)pe);
      bp[r]     = (short)(uint16_t)(hiTile ? (lo >> 16) : (lo & 0xFFFF));
      bp[4 + r] = (short)(uint16_t)(hiTile ? (hi >> 16) : (hi & 0xFFFF));
    }

    // PV: A=V (m=d), B=P (n=p) -> D row=d col=p
    #pragma unroll
    for (int dt = 0; dt < 8; ++dt)
      acc[dt] = __builtin_amdgcn_mfma_f32_16x16x32_bf16(av[dt], bp, acc[dt], 0, 0, 0);

    // ---- write next chunk to the other buffer ----
    if (li < NCHUNK - 1) {
      char* db = smem + ((li + 1) & 1) * BUFSZ;
      #pragma unroll
      for (int pass = 0; pass < 4; ++pass) {
        const int slot = pass * 256 + tid;
        if (pass < 2) {
          const int t = slot >> 8, r = (slot >> 4) & 15, sc = slot & 15;
          *(int4*)(db + t * KTILE + r * KPITCH + sc * 16) = pf[pass];
        } else {
          const int vs = slot - 512;
          const int h = vs >> 8, d = (vs >> 1) & 127, sc2 = vs & 1;
          *(int4*)(db + KBUF + d * VPITCH + (h * 2 + sc2) * 16) = pf[pass];
        }
      }
    }
    __syncthreads();
  }

  // ---- reduce Ssum across q-groups ----
  float sv = Ssum;
  sv += __shfl_xor(sv, 16);
  sv += __shfl_xor(sv, 32);

  if (PART) {
    // unnormalized partial: pacc[grp][d*16+ln], psum[grp][ln]
    const size_t grp = (((size_t)(b * KCLS + kc)) * 13 + pt) * 2 + half;
    float* pa = pacc + grp * 2048;
    #pragma unroll
    for (int dt = 0; dt < 8; ++dt)
      #pragma unroll
      for (int rr = 0; rr < 4; ++rr)
        pa[(dt * 16 + q * 4 + rr) * 16 + ln] = acc[dt][rr];
    if (q == 0) psum[grp * 16 + ln] = sv;
  } else {
    const float inv = 1.f / sv;
    const int pp = p0 + ln;
    if (pp < NP) {
      float* ob = out + ((size_t)(b * KCLS + kc) * ND + q * 4) * NP + pp;
      #pragma unroll
      for (int dt = 0; dt < 8; ++dt)
        #pragma unroll
        for (int rr = 0; rr < 4; ++rr)
          ob[(size_t)(dt * 16 + rr) * NP] = acc[dt][rr] * inv;
    }
  }
}

// ---------------------------------------------------------------------------
// Kernel 3: merge two halves + normalize. grid = 2080 (b*KCLS+kc, pt) x 256.
// thread (dr=tid>>4, ln=tid&15) handles 8 d-rows at col pt*16+ln.
// ---------------------------------------------------------------------------
__global__ __launch_bounds__(256) void merge_kernel(
    const float* __restrict__ pacc, const float* __restrict__ psum,
    float* __restrict__ out)
{
  const int bx = blockIdx.x;              // 2080 = 160 * 13
  const int pt = bx % 13;
  const int rem = bx / 13;                // b*KCLS + kc
  const int tid = (int)threadIdx.x;
  const int ln = tid & 15, dr = tid >> 4;
  const size_t g0 = (((size_t)rem) * 13 + pt) * 2;

  const float s = psum[g0 * 16 + ln] + psum[(g0 + 1) * 16 + ln];
  const int pp = pt * 16 + ln;
  if (pp >= NP) return;
  const float inv = 1.f / s;

  const float* pa0 = pacc + g0 * 2048;
  const float* pa1 = pacc + (g0 + 1) * 2048;
  float* ob = out + (size_t)rem * ND * NP + pp;
  #pragma unroll
  for (int i = 0; i < 8; ++i) {
    const int d = dr * 8 + i;
    ob[(size_t)d * NP] = (pa0[d * 16 + ln] + pa1[d * 16 + ln]) * inv;
  }
}

// ---------------------------------------------------------------------------
extern "C" void kernel_launch(void* const* d_in, const int* in_sizes, int n_in,
                              void* d_out, int out_size, void* d_ws, size_t ws_size,
                              hipStream_t stream) {
  const float* supp   = (const float*)d_in[0];
  const float* qry    = (const float*)d_in[1];
  const int*   labels = (const int*)d_in[2];
  const float* Wqk    = (const float*)d_in[3];
  const float* Wv     = (const float*)d_in[4];
  float* out = (float*)d_out;

  // ws layout: 4.53 MB staging + 34.3 MB partials (guarded)
  uint16_t* Whi = (uint16_t*)d_ws;                  // [2][128][512]
  uint16_t* Qt  = Whi + (size_t)2 * ND * NC;        // [32][196][128]
  uint16_t* Kt  = Qt  + (size_t)NB * NP * ND;       // [25][208][128]
  uint16_t* Vt  = Kt  + (size_t)NSUP * JS * ND;     // [25][128][208]
  float* pacc   = (float*)(Vt + (size_t)NSUP * ND * JS);
  float* psum   = pacc + PACC_F;
  const size_t need = (size_t)((char*)(psum + PSUM_F) - (char*)d_ws);
  float* outVq = out + (size_t)NB * KCLS * ND * NP; // query_v_flat region

  wconv_kernel<<<64, 256, 0, stream>>>(Wqk, Wv, Whi);
  gemm_kernel<<<741, 256, 0, stream>>>(supp, qry, Whi, Qt, Kt, Vt, outVq);
  if (ws_size >= need) {
    attn_kernel<17, true><<<1040, 256, 0, stream>>>(Qt, Kt, Vt, labels, out, pacc, psum);
    merge_kernel<<<2080, 256, 0, stream>>>(pacc, psum, out);
  } else {
    attn_kernel<33, false><<<520, 256, 0, stream>>>(Qt, Kt, Vt, labels, out, nullptr, nullptr);
  }
}

// Round 6
// 164.909 us; speedup vs baseline: 1.2820x; 1.0058x over previous
//
#include <hip/hip_runtime.h>
#include <cstdint>
#include <cstddef>

// Problem constants
#define NB   32    // query batch
#define NSUP 25    // support images
#define KCLS 5     // classes
#define NC   512   // input channels
#define ND   128   // dk = dv
#define NP   196   // h*w
#define JS   208   // per-support padded spatial (13*16)
#define SHIFT 8.0f // fixed logit shift (softmax-invariant overflow guard)

// attn LDS staging geometry (R0-verbatim)
#define KPITCH 272             // 256B K row + 16B pad (bank-stride 68 dw -> 2-way)
#define KTILE  (16 * KPITCH)   // 4352 B per 16-j K tile
#define KBUF   (2 * KTILE)     // 8704 B
#define VPITCH 80              // 64B V row + 16B pad (bank-stride 20 dw -> 2-way)
#define VBUF   (128 * VPITCH)  // 10240 B
#define BUFSZ  (KBUF + VBUF)   // 18944 B per buffer

#define NGRP   (NB * KCLS * 13)          // 2080 (b,kc,pt) groups
#define PACC_F ((size_t)NGRP * 2 * 2048) // partial acc floats (2 halves)
#define PSUM_F ((size_t)NGRP * 2 * 16)   // partial Ssum floats

typedef __attribute__((ext_vector_type(8))) short short8;   // 8 x bf16 (4 VGPRs)
typedef __attribute__((ext_vector_type(4))) float floatx4;  // MFMA C/D

__device__ inline short f2bf(float x) {
  union { float f; uint32_t u; } v; v.f = x;
  uint32_t r = (v.u + 0x7FFFu + ((v.u >> 16) & 1u)) >> 16;  // RNE
  return (short)(r & 0xFFFFu);
}
__device__ inline uint32_t pk2(float a, float b) {
  return (uint32_t)(uint16_t)f2bf(a) | ((uint32_t)(uint16_t)f2bf(b) << 16);
}

// ---------------------------------------------------------------------------
// Kernel 0: W fp32 -> bf16. Whi[mat][d:128][c:512], mats contiguous.
// ---------------------------------------------------------------------------
__global__ __launch_bounds__(256) void wconv_kernel(
    const float* __restrict__ Wqk, const float* __restrict__ Wv,
    uint16_t* __restrict__ Whi)
{
  const int f = (blockIdx.x * 256 + (int)threadIdx.x) * 8;   // < 131072
  const float* src = (f < ND * NC) ? (Wqk + f) : (Wv + f - ND * NC);
  short8 hv;
  #pragma unroll
  for (int i = 0; i < 8; ++i) hv[i] = f2bf(src[i]);
  *(short8*)(Whi + f) = hv;
}

// ---------------------------------------------------------------------------
// Kernel 1: fused projection GEMM (unchanged, verified).
//   QK: A=X(m=p), B=Wqk(n=d) -> bf16 Qt[b][p<196][d] / Kt[n][p:208][d]
//   V:  A=Wv(m=d), B=X(n=p)  -> bf16 Vt[n][d][p:208] / fp32 outVq[b][d][p]
// ---------------------------------------------------------------------------
__global__ __launch_bounds__(256) void gemm_kernel(
    const float* __restrict__ supp, const float* __restrict__ qry,
    const uint16_t* __restrict__ Whi,
    uint16_t* __restrict__ Qt, uint16_t* __restrict__ Kt,
    uint16_t* __restrict__ Vt, float* __restrict__ outVq)
{
  __shared__ uint16_t xs[16 * 520];     // 16.6 KB bf16 X tile, [p][c+pad]
  const int bx = blockIdx.x;
  const int t16 = bx % 13, img = bx / 13;
  const int tid = (int)threadIdx.x;
  const int w = tid >> 6, lane = tid & 63, ln = lane & 15, q = lane >> 4;
  const int d0 = w * 32;
  const int p0 = t16 * 16;

  const float* __restrict__ X = (img < NB)
      ? (qry  + (size_t)img * NC * NP)
      : (supp + (size_t)(img - NB) * NC * NP);

  // stage X tile as bf16: read float4 along p, write packed pairs along c
  #pragma unroll
  for (int k = 0; k < 4; ++k) {
    const int id = k * 256 + tid;
    const int cp = id >> 2;                        // c-pair: c = 2cp, 2cp+1
    const int pq = id & 3;
    int pg = p0 + pq * 4; if (pg > NP - 4) pg = NP - 4;   // clamp (pad rows masked later)
    const floatx4 fa = *(const floatx4*)(X + (2 * cp) * NP + pg);
    const floatx4 fb = *(const floatx4*)(X + (2 * cp + 1) * NP + pg);
    #pragma unroll
    for (int i = 0; i < 4; ++i)
      *((uint32_t*)xs + (pq * 4 + i) * 260 + cp) = pk2(fa[i], fb[i]);
  }
  __syncthreads();

  floatx4 aQ[2], aV[2];
  #pragma unroll
  for (int nt = 0; nt < 2; ++nt) {
    aQ[nt] = (floatx4){0.f, 0.f, 0.f, 0.f};
    aV[nt] = (floatx4){0.f, 0.f, 0.f, 0.f};
  }

  for (int ks = 0; ks < 16; ++ks) {
    const short8 xh = *(const short8*)&xs[ln * 520 + ks * 32 + q * 8];  // 1 ds_read_b128
    #pragma unroll
    for (int nt = 0; nt < 2; ++nt) {
      const size_t wr = (size_t)(d0 + nt * 16 + ln) * NC + ks * 32 + q * 8;
      const short8 wqh = *(const short8*)(Whi + wr);
      aQ[nt] = __builtin_amdgcn_mfma_f32_16x16x32_bf16(xh, wqh, aQ[nt], 0, 0, 0);
      const short8 wvh = *(const short8*)(Whi + (size_t)ND * NC + wr);
      aV[nt] = __builtin_amdgcn_mfma_f32_16x16x32_bf16(wvh, xh, aV[nt], 0, 0, 0);
    }
  }

  // QK: D row = p = p0+q*4+rr, col = d = d0+nt*16+ln
  if (img < NB) {
    #pragma unroll
    for (int nt = 0; nt < 2; ++nt)
      #pragma unroll
      for (int rr = 0; rr < 4; ++rr) {
        const int p = p0 + q * 4 + rr;
        if (p < NP)
          Qt[((size_t)img * NP + p) * ND + d0 + nt * 16 + ln] = (uint16_t)f2bf(aQ[nt][rr]);
      }
  } else {
    const int n = img - NB;
    #pragma unroll
    for (int nt = 0; nt < 2; ++nt)
      #pragma unroll
      for (int rr = 0; rr < 4; ++rr) {
        const int p = p0 + q * 4 + rr;              // 0..207, pads masked in attn
        Kt[((size_t)n * JS + p) * ND + d0 + nt * 16 + ln] = (uint16_t)f2bf(aQ[nt][rr]);
      }
  }
  // V: D row = d = d0+nt*16+q*4+rr, col = p = p0+ln
  const int p = p0 + ln;
  if (img < NB) {
    if (p < NP) {
      #pragma unroll
      for (int nt = 0; nt < 2; ++nt)
        #pragma unroll
        for (int rr = 0; rr < 4; ++rr)
          outVq[((size_t)img * ND + d0 + nt * 16 + q * 4 + rr) * NP + p] = aV[nt][rr];
    }
  } else {
    const int n = img - NB;
    #pragma unroll
    for (int nt = 0; nt < 2; ++nt)
      #pragma unroll
      for (int rr = 0; rr < 4; ++rr)
        Vt[((size_t)n * ND + d0 + nt * 16 + q * 4 + rr) * JS + p] = (uint16_t)f2bf(aV[nt][rr]);
  }
}

// ---------------------------------------------------------------------------
// Kernel 2: per-class masked attention. LDS-BOUND FIX: each wave now owns
// TWO batches (bA=b0+2w, bB=bA+1), so every bk/av LDS fragment read feeds
// 2x the MFMAs (32/chunk instead of 16) — halves the saturated LDS-pipe
// traffic per unit work. Block covers 8 batches; j-split in 2 halves kept
// (R5 merge path). Staging, slot decode, exp/bpermute/PV math R0-verbatim,
// duplicated per-b. grid = 13pt * 5kc * (4oct * 2half) = 520 x 256.
// PART=false fallback: same kernel, grid 260, 34 chunks (ws-too-small).
// ---------------------------------------------------------------------------
template <int NCHUNK, bool PART>
__global__ __launch_bounds__(256, 2) void attn_kernel(
    const uint16_t* __restrict__ Qt, const uint16_t* __restrict__ Kt,
    const uint16_t* __restrict__ Vt, const int* __restrict__ labels,
    float* __restrict__ out, float* __restrict__ pacc, float* __restrict__ psum)
{
  __shared__ __align__(16) char smem[2 * BUFSZ];   // 37.9 KB double buffer

  const int bx = blockIdx.x;
  const int pt = bx % 13;
  const int rem = bx / 13;                // PART: 40 = 5*(4*2) ; full: 20 = 5*4
  const int kc = rem % KCLS;
  const int rest = rem / KCLS;            // PART: 0..7 ; full: 0..3
  const int oct = PART ? (rest & 3) : rest;
  const int half = PART ? (rest >> 2) : 0;
  const int c0 = half * NCHUNK;           // chunk range [c0, c0+NCHUNK)
  const int b0 = oct * 8;                 // batch octet base
  const int p0 = pt * 16;
  const int tid = (int)threadIdx.x;
  const int w = tid >> 6, lane = tid & 63, ln = lane & 15, q = lane >> 4;
  const int bA = b0 + w * 2, bB = bA + 1; // this wave's two batches

  // class-support list packed in a register (6 bits/slot) via ballot
  const int myl = (lane < NSUP) ? labels[lane] : -1;
  unsigned long long m = __ballot(myl == kc);
  int clsPack = 0;
  #pragma unroll
  for (int s = 0; s < 5; ++s) {
    const int n = (m != 0ull) ? (int)__builtin_ctzll(m) : 0;
    clsPack |= n << (6 * s);
    m &= (m - 1);
  }

  // Q B-frags (resident), per batch: B[n=p][k=d]
  short8 aqA[4], aqB[4];
  {
    int p = p0 + ln; if (p > NP - 1) p = NP - 1;
    const uint16_t* baseA = Qt + ((size_t)bA * NP + p) * ND + q * 8;
    const uint16_t* baseB = Qt + ((size_t)bB * NP + p) * ND + q * 8;
    #pragma unroll
    for (int ks = 0; ks < 4; ++ks) {
      aqA[ks] = *(const short8*)(baseA + ks * 32);
      aqB[ks] = *(const short8*)(baseB + ks * 32);
    }
  }

  floatx4 accA[8], accB[8];
  #pragma unroll
  for (int dt = 0; dt < 8; ++dt) {
    accA[dt] = (floatx4){0.f, 0.f, 0.f, 0.f};
    accB[dt] = (floatx4){0.f, 0.f, 0.f, 0.f};
  }
  float SsA = 0.f, SsB = 0.f;

  const int alo = (ln + ((q & 1) << 5)) << 2;  // bpermute byte addr (verified)
  const bool hiTile = (q >= 2);

  // ---- chunk staging (R0-verbatim slots; chunk index offset by c0) ----
  // K: slots 0..511:  t=slot>>8, r=(slot>>4)&15, sc=slot&15
  // V: slots 512..1023: h, d, sc2 -> scol = h*2+sc2
  int4 pf[4];
  {
    // prefetch chunk c0
    int nk[2], j0k[2], nv[2], jv[2];
    #pragma unroll
    for (int t = 0; t < 2; ++t) {
      const int tile16 = c0 * 2 + t;
      int s = tile16 / 13;
      j0k[t] = (tile16 - s * 13) * 16;
      if (s > 4) s = 4;
      nk[t] = (clsPack >> (6 * s)) & 63;
    }
    #pragma unroll
    for (int h = 0; h < 2; ++h) {
      const int ch = c0 * 32 + h * 16;
      int sv = ch / JS, jvv = ch - sv * JS;
      if (sv > 4) { sv = 4; jvv = 192; }
      nv[h] = (clsPack >> (6 * sv)) & 63;
      jv[h] = jvv;
    }
    #pragma unroll
    for (int pass = 0; pass < 4; ++pass) {
      const int slot = pass * 256 + tid;
      if (pass < 2) {
        const int t = slot >> 8, r = (slot >> 4) & 15, sc = slot & 15;
        pf[pass] = *(const int4*)(Kt + ((size_t)(nk[t] * JS + j0k[t] + r)) * ND + sc * 8);
      } else {
        const int vs = slot - 512;
        const int h = vs >> 8, d = (vs >> 1) & 127, sc2 = vs & 1;
        pf[pass] = *(const int4*)(Vt + ((size_t)(nv[h] * ND + d)) * JS + jv[h] + sc2 * 8);
      }
    }
    char* db = smem;                    // buffer 0
    #pragma unroll
    for (int pass = 0; pass < 4; ++pass) {
      const int slot = pass * 256 + tid;
      if (pass < 2) {
        const int t = slot >> 8, r = (slot >> 4) & 15, sc = slot & 15;
        *(int4*)(db + t * KTILE + r * KPITCH + sc * 16) = pf[pass];
      } else {
        const int vs = slot - 512;
        const int h = vs >> 8, d = (vs >> 1) & 127, sc2 = vs & 1;
        *(int4*)(db + KBUF + d * VPITCH + (h * 2 + sc2) * 16) = pf[pass];
      }
    }
  }
  __syncthreads();

  for (int li = 0; li < NCHUNK; ++li) {
    const int cc = c0 + li;               // current chunk
    const int nc = cc + 1;                // next chunk
    int nk[2], j0k[2], nv[2], jv[2];
    if (li < NCHUNK - 1) {                // issue next chunk's global loads early
      #pragma unroll
      for (int t = 0; t < 2; ++t) {
        const int tile16 = nc * 2 + t;
        int s = tile16 / 13;
        j0k[t] = (tile16 - s * 13) * 16;
        if (s > 4) s = 4;
        nk[t] = (clsPack >> (6 * s)) & 63;
      }
      #pragma unroll
      for (int h = 0; h < 2; ++h) {
        const int ch = nc * 32 + h * 16;
        int sv = ch / JS, jvv = ch - sv * JS;
        if (sv > 4) { sv = 4; jvv = 192; }
        nv[h] = (clsPack >> (6 * sv)) & 63;
        jv[h] = jvv;
      }
      #pragma unroll
      for (int pass = 0; pass < 4; ++pass) {
        const int slot = pass * 256 + tid;
        if (pass < 2) {
          const int t = slot >> 8, r = (slot >> 4) & 15, sc = slot & 15;
          pf[pass] = *(const int4*)(Kt + ((size_t)(nk[t] * JS + j0k[t] + r)) * ND + sc * 8);
        } else {
          const int vs = slot - 512;
          const int h = vs >> 8, d = (vs >> 1) & 127, sc2 = vs & 1;
          pf[pass] = *(const int4*)(Vt + ((size_t)(nv[h] * ND + d)) * JS + jv[h] + sc2 * 8);
        }
      }
    }

    // ---- compute chunk `cc` from buffer li&1 (fragments read ONCE, 2 b's) ----
    const char* kb = smem + (li & 1) * BUFSZ;
    const char* vb = kb + KBUF;

    short8 av[8];
    #pragma unroll
    for (int dt = 0; dt < 8; ++dt)
      av[dt] = *(const short8*)(vb + (dt * 16 + ln) * VPITCH + q * 16);

    short8 bk[2][4];
    #pragma unroll
    for (int t = 0; t < 2; ++t)
      #pragma unroll
      for (int ks = 0; ks < 4; ++ks)
        bk[t][ks] = *(const short8*)(kb + t * KTILE + ln * KPITCH + ks * 64 + q * 16);

    // QK as S^T (A=K m=j, B=Q n=p), exp with pad masking (R0 verbatim, x2 b)
    floatx4 e0A, e1A, e0B, e1B;
    #pragma unroll
    for (int t = 0; t < 2; ++t) {
      const int tile16 = cc * 2 + t;
      const int s = tile16 / 13;
      const int j0 = (tile16 - s * 13) * 16;
      const bool tval = (s < 5);
      floatx4 d4A = {0.f, 0.f, 0.f, 0.f};
      floatx4 d4B = {0.f, 0.f, 0.f, 0.f};
      #pragma unroll
      for (int ks = 0; ks < 4; ++ks) {
        d4A = __builtin_amdgcn_mfma_f32_16x16x32_bf16(bk[t][ks], aqA[ks], d4A, 0, 0, 0);
        d4B = __builtin_amdgcn_mfma_f32_16x16x32_bf16(bk[t][ks], aqB[ks], d4B, 0, 0, 0);
      }
      floatx4 evA, evB;
      #pragma unroll
      for (int r = 0; r < 4; ++r) {
        const int j = j0 + q * 4 + r;
        const bool val = (tval && j < NP);
        const float eA = val ? __expf(d4A[r] - SHIFT) : 0.f;
        const float eB = val ? __expf(d4B[r] - SHIFT) : 0.f;
        evA[r] = eA; SsA += eA;
        evB[r] = eB; SsB += eB;
      }
      if (t == 0) { e0A = evA; e0B = evB; } else { e1A = evA; e1B = evB; }
    }

    // D-layout -> B-operand transform (R0-verbatim packed exchange, x2 b)
    short8 bpA, bpB;
    #pragma unroll
    for (int r = 0; r < 4; ++r) {
      const uint32_t peA = pk2(e0A[r], e1A[r]);
      const int loA = __builtin_amdgcn_ds_bpermute(alo, (int)peA);
      const int hiA = __builtin_amdgcn_ds_bpermute(alo + 64, (int)peA);
      bpA[r]     = (short)(uint16_t)(hiTile ? (loA >> 16) : (loA & 0xFFFF));
      bpA[4 + r] = (short)(uint16_t)(hiTile ? (hiA >> 16) : (hiA & 0xFFFF));
      const uint32_t peB = pk2(e0B[r], e1B[r]);
      const int loB = __builtin_amdgcn_ds_bpermute(alo, (int)peB);
      const int hiB = __builtin_amdgcn_ds_bpermute(alo + 64, (int)peB);
      bpB[r]     = (short)(uint16_t)(hiTile ? (loB >> 16) : (loB & 0xFFFF));
      bpB[4 + r] = (short)(uint16_t)(hiTile ? (hiB >> 16) : (hiB & 0xFFFF));
    }

    // PV: A=V (m=d), B=P (n=p) -> D row=d col=p (av reused for both b's)
    #pragma unroll
    for (int dt = 0; dt < 8; ++dt) {
      accA[dt] = __builtin_amdgcn_mfma_f32_16x16x32_bf16(av[dt], bpA, accA[dt], 0, 0, 0);
      accB[dt] = __builtin_amdgcn_mfma_f32_16x16x32_bf16(av[dt], bpB, accB[dt], 0, 0, 0);
    }

    // ---- write next chunk to the other buffer ----
    if (li < NCHUNK - 1) {
      char* db = smem + ((li + 1) & 1) * BUFSZ;
      #pragma unroll
      for (int pass = 0; pass < 4; ++pass) {
        const int slot = pass * 256 + tid;
        if (pass < 2) {
          const int t = slot >> 8, r = (slot >> 4) & 15, sc = slot & 15;
          *(int4*)(db + t * KTILE + r * KPITCH + sc * 16) = pf[pass];
        } else {
          const int vs = slot - 512;
          const int h = vs >> 8, d = (vs >> 1) & 127, sc2 = vs & 1;
          *(int4*)(db + KBUF + d * VPITCH + (h * 2 + sc2) * 16) = pf[pass];
        }
      }
    }
    __syncthreads();
  }

  // ---- reduce Ssum across q-groups (per b) ----
  float svA = SsA;
  svA += __shfl_xor(svA, 16);
  svA += __shfl_xor(svA, 32);
  float svB = SsB;
  svB += __shfl_xor(svB, 16);
  svB += __shfl_xor(svB, 32);

  if (PART) {
    // unnormalized partials: pacc[grp][d*16+ln], psum[grp][ln]
    const size_t grpA = (((size_t)(bA * KCLS + kc)) * 13 + pt) * 2 + half;
    const size_t grpB = (((size_t)(bB * KCLS + kc)) * 13 + pt) * 2 + half;
    float* paA = pacc + grpA * 2048;
    float* paB = pacc + grpB * 2048;
    #pragma unroll
    for (int dt = 0; dt < 8; ++dt)
      #pragma unroll
      for (int rr = 0; rr < 4; ++rr) {
        paA[(dt * 16 + q * 4 + rr) * 16 + ln] = accA[dt][rr];
        paB[(dt * 16 + q * 4 + rr) * 16 + ln] = accB[dt][rr];
      }
    if (q == 0) {
      psum[grpA * 16 + ln] = svA;
      psum[grpB * 16 + ln] = svB;
    }
  } else {
    const int pp = p0 + ln;
    if (pp < NP) {
      const float invA = 1.f / svA, invB = 1.f / svB;
      float* obA = out + ((size_t)(bA * KCLS + kc) * ND + q * 4) * NP + pp;
      float* obB = out + ((size_t)(bB * KCLS + kc) * ND + q * 4) * NP + pp;
      #pragma unroll
      for (int dt = 0; dt < 8; ++dt)
        #pragma unroll
        for (int rr = 0; rr < 4; ++rr) {
          obA[(size_t)(dt * 16 + rr) * NP] = accA[dt][rr] * invA;
          obB[(size_t)(dt * 16 + rr) * NP] = accB[dt][rr] * invB;
        }
    }
  }
}

// ---------------------------------------------------------------------------
// Kernel 3: merge two halves + normalize. grid = 2080 (b*KCLS+kc, pt) x 256.
// thread (dr=tid>>4, ln=tid&15) handles 8 d-rows at col pt*16+ln.
// ---------------------------------------------------------------------------
__global__ __launch_bounds__(256) void merge_kernel(
    const float* __restrict__ pacc, const float* __restrict__ psum,
    float* __restrict__ out)
{
  const int bx = blockIdx.x;              // 2080 = 160 * 13
  const int pt = bx % 13;
  const int rem = bx / 13;                // b*KCLS + kc
  const int tid = (int)threadIdx.x;
  const int ln = tid & 15, dr = tid >> 4;
  const size_t g0 = (((size_t)rem) * 13 + pt) * 2;

  const float s = psum[g0 * 16 + ln] + psum[(g0 + 1) * 16 + ln];
  const int pp = pt * 16 + ln;
  if (pp >= NP) return;
  const float inv = 1.f / s;

  const float* pa0 = pacc + g0 * 2048;
  const float* pa1 = pacc + (g0 + 1) * 2048;
  float* ob = out + (size_t)rem * ND * NP + pp;
  #pragma unroll
  for (int i = 0; i < 8; ++i) {
    const int d = dr * 8 + i;
    ob[(size_t)d * NP] = (pa0[d * 16 + ln] + pa1[d * 16 + ln]) * inv;
  }
}

// ---------------------------------------------------------------------------
extern "C" void kernel_launch(void* const* d_in, const int* in_sizes, int n_in,
                              void* d_out, int out_size, void* d_ws, size_t ws_size,
                              hipStream_t stream) {
  const float* supp   = (const float*)d_in[0];
  const float* qry    = (const float*)d_in[1];
  const int*   labels = (const int*)d_in[2];
  const float* Wqk    = (const float*)d_in[3];
  const float* Wv     = (const float*)d_in[4];
  float* out = (float*)d_out;

  // ws layout: 4.53 MB staging + 34.3 MB partials (guarded)
  uint16_t* Whi = (uint16_t*)d_ws;                  // [2][128][512]
  uint16_t* Qt  = Whi + (size_t)2 * ND * NC;        // [32][196][128]
  uint16_t* Kt  = Qt  + (size_t)NB * NP * ND;       // [25][208][128]
  uint16_t* Vt  = Kt  + (size_t)NSUP * JS * ND;     // [25][128][208]
  float* pacc   = (float*)(Vt + (size_t)NSUP * ND * JS);
  float* psum   = pacc + PACC_F;
  const size_t need = (size_t)((char*)(psum + PSUM_F) - (char*)d_ws);
  float* outVq = out + (size_t)NB * KCLS * ND * NP; // query_v_flat region

  wconv_kernel<<<64, 256, 0, stream>>>(Wqk, Wv, Whi);
  gemm_kernel<<<741, 256, 0, stream>>>(supp, qry, Whi, Qt, Kt, Vt, outVq);
  if (ws_size >= need) {
    attn_kernel<17, true><<<520, 256, 0, stream>>>(Qt, Kt, Vt, labels, out, pacc, psum);
    merge_kernel<<<2080, 256, 0, stream>>>(pacc, psum, out);
  } else {
    attn_kernel<34, false><<<260, 256, 0, stream>>>(Qt, Kt, Vt, labels, out, nullptr, nullptr);
  }
}